// Round 6
// baseline (320.628 us; speedup 1.0000x reference)
//
#include <hip/hip_runtime.h>
#include <math.h>

typedef _Float16 f16;
typedef f16 f16x8 __attribute__((ext_vector_type(8)));
typedef float f32x16 __attribute__((ext_vector_type(16)));

static constexpr int Bn = 16;
static constexpr int Kn = 4096;
static constexpr int NPTS = Bn * Kn;    // 65536
static constexpr int MGRID = 1024;      // qg(32) x b(16) x dir(2)
static constexpr float WBIG = 49152.0f; // exact in fp16
static constexpr float QMIN0 = 3e37f;

static constexpr size_t FRAG_BYTES = (size_t)NPTS * 32;

// 16 K-slot values (13 used) for v_mfma_f32_32x32x16_f16:
// d2[r][q] = sum_k A[r][k]*B[k][q]
//  k0..8 : error-compensated -2*dot (hh, hl, lh per coord)
//  k9,10 : ref ||.||^2 (hi,lo) * 1 ;  k11,12: 1 * query ||.||^2 (hi,lo)
// invalid as ref: w=+WBIG (never wins min); invalid as query: w=-WBIG
// (min << -1e4 -> dropped at the sqrt stage).
__device__ inline void mk_slots(float x, float y, float z, bool valid,
                                f16 A[16], f16 B[16]) {
    float w = fmaf(x, x, fmaf(y, y, z * z));
    f16 xh = (f16)x, yh = (f16)y, zh = (f16)z;
    f16 xl = (f16)(x - (float)xh), yl = (f16)(y - (float)yh), zl = (f16)(z - (float)zh);
    f16 m2xh = (f16)(-2.0f * (float)xh), m2xl = (f16)(-2.0f * (float)xl);
    f16 m2yh = (f16)(-2.0f * (float)yh), m2yl = (f16)(-2.0f * (float)yl);
    f16 m2zh = (f16)(-2.0f * (float)zh), m2zl = (f16)(-2.0f * (float)zl);
    f16 one = (f16)1.0f, zero = (f16)0.0f;
    f16 whA, wlA, whB, wlB;
    if (valid) {
        f16 wh = (f16)w; f16 wl = (f16)(w - (float)wh);
        whA = wh; wlA = wl; whB = wh; wlB = wl;
    } else {
        whA = (f16)WBIG;   wlA = zero;
        whB = (f16)(-WBIG); wlB = zero;
    }
    A[0] = m2xh; A[1] = m2xh; A[2] = m2xl;
    A[3] = m2yh; A[4] = m2yh; A[5] = m2yl;
    A[6] = m2zh; A[7] = m2zh; A[8] = m2zl;
    A[9] = whA; A[10] = wlA; A[11] = one; A[12] = one;
    A[13] = zero; A[14] = zero; A[15] = zero;
    B[0] = xh; B[1] = xl; B[2] = xh;
    B[3] = yh; B[4] = yl; B[5] = yh;
    B[6] = zh; B[7] = zl; B[8] = zh;
    B[9] = one; B[10] = one; B[11] = whB; B[12] = wlB;
    B[13] = zero; B[14] = zero; B[15] = zero;
}

// 32x32x16 tile = 64 entries of f16x8. Lane l -> row/col = l&31, k-group
// g = l>>5. Entry index: g*32 + r. A-slot j and B-slot j at the same (g, i)
// position -> products pair under any shared k-bijection.
// Also writes the opaque 64-B zero block for the mfma kernel's C operand.
__global__ __launch_bounds__(256) void prep_kernel(
        const float* __restrict__ pred, const float* __restrict__ target,
        const int* __restrict__ mask,
        f16x8* __restrict__ predA, f16x8* __restrict__ predB,
        f16x8* __restrict__ tgtA, f16x8* __restrict__ tgtB,
        unsigned int* __restrict__ cnt4, float* __restrict__ czero) {
    int idx = blockIdx.x * 256 + threadIdx.x;
    if (idx < 16) czero[idx] = 0.0f;
    bool valid = mask[idx] != 0;

    float px = pred[idx * 3 + 0], py = pred[idx * 3 + 1], pz = pred[idx * 3 + 2];
    float tx = target[idx * 3 + 0], ty = target[idx * 3 + 1], tz = target[idx * 3 + 2];
    if (!valid) { px = py = pz = 0.0f; tx = ty = tz = 0.0f; }

    f16 PA[16], PB[16], TA[16], TB[16];
    mk_slots(px, py, pz, valid, PA, PB);
    mk_slots(tx, ty, tz, valid, TA, TB);

    int b = idx >> 12, kk = idx & 4095;
    int rt = kk >> 5, r = kk & 31;
    size_t base = ((size_t)(b * 128 + rt)) * 64;

    #pragma unroll
    for (int g = 0; g < 2; ++g) {
        int o = g * 8;
        predA[base + g * 32 + r] = (f16x8){PA[o+0],PA[o+1],PA[o+2],PA[o+3],PA[o+4],PA[o+5],PA[o+6],PA[o+7]};
        predB[base + g * 32 + r] = (f16x8){PB[o+0],PB[o+1],PB[o+2],PB[o+3],PB[o+4],PB[o+5],PB[o+6],PB[o+7]};
        tgtA[base + g * 32 + r]  = (f16x8){TA[o+0],TA[o+1],TA[o+2],TA[o+3],TA[o+4],TA[o+5],TA[o+6],TA[o+7]};
        tgtB[base + g * 32 + r]  = (f16x8){TB[o+0],TB[o+1],TB[o+2],TB[o+3],TB[o+4],TB[o+5],TB[o+6],TB[o+7]};
    }

    unsigned long long mb = __ballot(valid);
    if ((threadIdx.x & 63) == 0)
        cnt4[idx >> 6] = (unsigned int)__popcll(mb);
}

// Round-6: r5 structure (swizzle kept, (256,4), qt=4, 1024 blocks) + ONE
// change: explicit software pipelining of the A-stream. At VGPR=40 the
// compiler loaded each a-tile right before its MFMA group -> a naked
// ~200-cyc L2-hit latency per 4-MFMA group, only partially covered by 4
// waves/SIMD. Now: rotating group-of-4 prefetch, fully unrolled (all
// indices compile-time -> registers, no scratch). Next 4 loads issue
// BEFORE computing the current 4 -> 4-8 loads in flight, latency hidden
// under ~384 cyc of MFMA+min3 work. Uses ~80 VGPR, under the 128 cap at
// (256,4) -> occupancy unchanged. Compute order (t asc, qt, i) unchanged
// -> bitwise-identical output.
__global__ __launch_bounds__(256, 4) void chamfer_mfma_kernel(
        const f16x8* __restrict__ predA, const f16x8* __restrict__ predB,
        const f16x8* __restrict__ tgtA, const f16x8* __restrict__ tgtB,
        const float* __restrict__ czero, float* __restrict__ psum) {
    int bid = blockIdx.x;
    int lin = (bid & 7) * 128 + (bid >> 3);   // XCD-contiguous logical id
    int pidx = lin;                           // psum slot = logical id
    int qg = lin & 31; lin >>= 5;             // qg(32) fastest, b(16), dir(2)
    int b  = lin & 15; lin >>= 4;
    int dir = lin;                            // 0: queries=pred, refs=target

    const f16x8* __restrict__ Apack = dir ? predA : tgtA;  // refs
    const f16x8* __restrict__ Bpack = dir ? tgtB  : predB; // queries

    int tid = threadIdx.x;
    int w = tid >> 6, l = tid & 63;

    __shared__ float comb[4][4][64];

    f16x8 bq[4];
    #pragma unroll
    for (int qt = 0; qt < 4; ++qt)
        bq[qt] = Bpack[((size_t)(b * 128 + qg * 4 + qt)) * 64 + l];

    // opaque zero C-operand (value IS zero; provenance hidden from compiler)
    f32x16 cz = *(const f32x16*)czero;

    float qA[4], qB[4];
    #pragma unroll
    for (int qt = 0; qt < 4; ++qt) { qA[qt] = QMIN0; qB[qt] = QMIN0; }

    auto step = [&](const f16x8& a) {
        #pragma unroll
        for (int qt = 0; qt < 4; ++qt) {
            f32x16 d = __builtin_amdgcn_mfma_f32_32x32x16_f16(a, bq[qt], cz, 0, 0, 0);
            #pragma unroll
            for (int i = 0; i < 4; ++i) {
                qA[qt] = fminf(fminf(qA[qt], d[4 * i + 0]), d[4 * i + 1]);  // -> v_min3
                qB[qt] = fminf(fminf(qB[qt], d[4 * i + 2]), d[4 * i + 3]);  // -> v_min3
            }
        }
    };

    size_t abase = ((size_t)(b * 128)) * 64 + (size_t)w * 64 + l;
    // prologue: first group of 4 a-tiles in flight
    f16x8 ac0 = Apack[abase + (size_t)0 * 256];
    f16x8 ac1 = Apack[abase + (size_t)1 * 256];
    f16x8 ac2 = Apack[abase + (size_t)2 * 256];
    f16x8 ac3 = Apack[abase + (size_t)3 * 256];
    #pragma unroll
    for (int tt = 0; tt < 8; ++tt) {
        f16x8 an0, an1, an2, an3;
        if (tt < 7) {   // compile-time after unroll
            size_t nb = abase + (size_t)(tt * 4 + 4) * 256;
            an0 = Apack[nb + (size_t)0 * 256];
            an1 = Apack[nb + (size_t)1 * 256];
            an2 = Apack[nb + (size_t)2 * 256];
            an3 = Apack[nb + (size_t)3 * 256];
        }
        step(ac0); step(ac1); step(ac2); step(ac3);
        if (tt < 7) { ac0 = an0; ac1 = an1; ac2 = an2; ac3 = an3; }
    }

    #pragma unroll
    for (int qt = 0; qt < 4; ++qt) comb[w][qt][l] = fminf(qA[qt], qB[qt]);
    __syncthreads();

    float contrib = 0.0f;
    if (tid < 128) {
        int qt = tid >> 5, c = tid & 31;
        float m = QMIN0;
        #pragma unroll
        for (int ww = 0; ww < 4; ++ww)
            #pragma unroll
            for (int h = 0; h < 2; ++h)
                m = fminf(m, comb[ww][qt][h * 32 + c]);
        // m < -1e4 marks an invalid query (w_q = -WBIG); contributes 0
        contrib = (m < -1e4f) ? 0.0f : sqrtf(fmaxf(m, 1e-12f));
    }
    for (int off = 32; off; off >>= 1)
        contrib += __shfl_down(contrib, off, 64);
    __shared__ float ps[4];
    if ((tid & 63) == 0) ps[tid >> 6] = contrib;
    __syncthreads();
    if (tid == 0)
        psum[pidx] = ps[0] + ps[1] + ps[2] + ps[3];
}

__global__ __launch_bounds__(256) void final_kernel(
        const unsigned int* __restrict__ cnt4, const float* __restrict__ psum,
        float* __restrict__ out) {
    int t = threadIdx.x;
    unsigned int c = 0;
    float s = 0.0f;
    #pragma unroll
    for (int i = 0; i < 4; ++i) {
        c += cnt4[t + 256 * i];
        s += psum[t + 256 * i];
    }
    for (int off = 32; off; off >>= 1) {
        c += __shfl_down(c, off, 64);
        s += __shfl_down(s, off, 64);
    }
    __shared__ unsigned int cs[4];
    __shared__ float ss[4];
    if ((t & 63) == 0) { cs[t >> 6] = c; ss[t >> 6] = s; }
    __syncthreads();
    if (t == 0) {
        unsigned int C = cs[0] + cs[1] + cs[2] + cs[3];
        float S = ss[0] + ss[1] + ss[2] + ss[3];
        out[0] = S * 0.5f / ((float)C + 1e-8f);
    }
}

extern "C" void kernel_launch(void* const* d_in, const int* in_sizes, int n_in,
                              void* d_out, int out_size, void* d_ws, size_t ws_size,
                              hipStream_t stream) {
    const float* pred = (const float*)d_in[0];
    const float* target = (const float*)d_in[1];
    const int* mask = (const int*)d_in[2];
    float* out = (float*)d_out;

    // ws: [predA 2M | predB 2M | tgtA 2M | tgtB 2M | psum 4K | cnt4 4K | czero 64B]
    char* ws = (char*)d_ws;
    size_t off = 0;
    f16x8* predA = (f16x8*)(ws + off); off += FRAG_BYTES;
    f16x8* predB = (f16x8*)(ws + off); off += FRAG_BYTES;
    f16x8* tgtA  = (f16x8*)(ws + off); off += FRAG_BYTES;
    f16x8* tgtB  = (f16x8*)(ws + off); off += FRAG_BYTES;
    float* psum = (float*)(ws + off); off += MGRID * sizeof(float);
    unsigned int* cnt4 = (unsigned int*)(ws + off); off += 1024 * sizeof(unsigned int);
    float* czero = (float*)(ws + off);

    prep_kernel<<<NPTS / 256, 256, 0, stream>>>(
        pred, target, mask, predA, predB, tgtA, tgtB, cnt4, czero);
    chamfer_mfma_kernel<<<MGRID, 256, 0, stream>>>(
        predA, predB, tgtA, tgtB, czero, psum);
    final_kernel<<<1, 256, 0, stream>>>(cnt4, psum, out);
}

// Round 7
// 28.318 us; speedup vs baseline: 11.3223x; 11.3223x over previous
//
#include <hip/hip_runtime.h>
#include <math.h>

typedef _Float16 f16;
typedef f16 f16x8 __attribute__((ext_vector_type(8)));
typedef float f32x16 __attribute__((ext_vector_type(16)));

static constexpr int Bn = 16;
static constexpr int Kn = 4096;
static constexpr int NPTS = Bn * Kn;    // 65536
static constexpr int MGRID = 512;       // qg8(16) x b(16) x dir(2)
static constexpr int NPSUM = 1024;      // psum keeps the OLD 1024-slot layout
static constexpr float WBIG = 49152.0f; // exact in fp16
static constexpr float QMIN0 = 3e37f;

static constexpr size_t FRAG_BYTES = (size_t)NPTS * 32;

// 16 K-slot values (13 used) for v_mfma_f32_32x32x16_f16:
// d2[r][q] = sum_k A[r][k]*B[k][q]
//  k0..8 : error-compensated -2*dot (hh, hl, lh per coord)
//  k9,10 : ref ||.||^2 (hi,lo) * 1 ;  k11,12: 1 * query ||.||^2 (hi,lo)
// invalid as ref: w=+WBIG (never wins min); invalid as query: w=-WBIG
// (min << -1e4 -> dropped at the sqrt stage).
__device__ inline void mk_slots(float x, float y, float z, bool valid,
                                f16 A[16], f16 B[16]) {
    float w = fmaf(x, x, fmaf(y, y, z * z));
    f16 xh = (f16)x, yh = (f16)y, zh = (f16)z;
    f16 xl = (f16)(x - (float)xh), yl = (f16)(y - (float)yh), zl = (f16)(z - (float)zh);
    f16 m2xh = (f16)(-2.0f * (float)xh), m2xl = (f16)(-2.0f * (float)xl);
    f16 m2yh = (f16)(-2.0f * (float)yh), m2yl = (f16)(-2.0f * (float)yl);
    f16 m2zh = (f16)(-2.0f * (float)zh), m2zl = (f16)(-2.0f * (float)zl);
    f16 one = (f16)1.0f, zero = (f16)0.0f;
    f16 whA, wlA, whB, wlB;
    if (valid) {
        f16 wh = (f16)w; f16 wl = (f16)(w - (float)wh);
        whA = wh; wlA = wl; whB = wh; wlB = wl;
    } else {
        whA = (f16)WBIG;   wlA = zero;
        whB = (f16)(-WBIG); wlB = zero;
    }
    A[0] = m2xh; A[1] = m2xh; A[2] = m2xl;
    A[3] = m2yh; A[4] = m2yh; A[5] = m2yl;
    A[6] = m2zh; A[7] = m2zh; A[8] = m2zl;
    A[9] = whA; A[10] = wlA; A[11] = one; A[12] = one;
    A[13] = zero; A[14] = zero; A[15] = zero;
    B[0] = xh; B[1] = xl; B[2] = xh;
    B[3] = yh; B[4] = yl; B[5] = yh;
    B[6] = zh; B[7] = zl; B[8] = zh;
    B[9] = one; B[10] = one; B[11] = whB; B[12] = wlB;
    B[13] = zero; B[14] = zero; B[15] = zero;
}

// 32x32x16 tile = 64 entries of f16x8. Lane l -> row/col = l&31, k-group
// g = l>>5. Entry index: g*32 + r. A-slot j and B-slot j at the same (g, i)
// position -> products pair under any shared k-bijection.
// Also writes the opaque 64-B zero block for the mfma kernel's C operand.
__global__ __launch_bounds__(256) void prep_kernel(
        const float* __restrict__ pred, const float* __restrict__ target,
        const int* __restrict__ mask,
        f16x8* __restrict__ predA, f16x8* __restrict__ predB,
        f16x8* __restrict__ tgtA, f16x8* __restrict__ tgtB,
        unsigned int* __restrict__ cnt4, float* __restrict__ czero) {
    int idx = blockIdx.x * 256 + threadIdx.x;
    if (idx < 16) czero[idx] = 0.0f;
    bool valid = mask[idx] != 0;

    float px = pred[idx * 3 + 0], py = pred[idx * 3 + 1], pz = pred[idx * 3 + 2];
    float tx = target[idx * 3 + 0], ty = target[idx * 3 + 1], tz = target[idx * 3 + 2];
    if (!valid) { px = py = pz = 0.0f; tx = ty = tz = 0.0f; }

    f16 PA[16], PB[16], TA[16], TB[16];
    mk_slots(px, py, pz, valid, PA, PB);
    mk_slots(tx, ty, tz, valid, TA, TB);

    int b = idx >> 12, kk = idx & 4095;
    int rt = kk >> 5, r = kk & 31;
    size_t base = ((size_t)(b * 128 + rt)) * 64;

    #pragma unroll
    for (int g = 0; g < 2; ++g) {
        int o = g * 8;
        predA[base + g * 32 + r] = (f16x8){PA[o+0],PA[o+1],PA[o+2],PA[o+3],PA[o+4],PA[o+5],PA[o+6],PA[o+7]};
        predB[base + g * 32 + r] = (f16x8){PB[o+0],PB[o+1],PB[o+2],PB[o+3],PB[o+4],PB[o+5],PB[o+6],PB[o+7]};
        tgtA[base + g * 32 + r]  = (f16x8){TA[o+0],TA[o+1],TA[o+2],TA[o+3],TA[o+4],TA[o+5],TA[o+6],TA[o+7]};
        tgtB[base + g * 32 + r]  = (f16x8){TB[o+0],TB[o+1],TB[o+2],TB[o+3],TB[o+4],TB[o+5],TB[o+6],TB[o+7]};
    }

    unsigned long long mb = __ballot(valid);
    if ((threadIdx.x & 63) == 0)
        cnt4[idx >> 6] = (unsigned int)__popcll(mb);
}

// Round-7: qt=8 / 512 blocks. Each block = two old logical blocks (2k,2k+1):
// 8 query-tiles share each a-tile load -> A-traffic halves (67 MB) and
// MFMA-per-load doubles (8 MFMAs = 256 SIMD-cyc of latency coverage).
// Loop SHAPE identical to the proven r5 kernel (plain loop, loads in-loop,
// no manual pipelining — R4/R6 showed hand-rotation => allocator clamp +
// scratch spill). De-risk the clamp: grid 512 = exactly 2 blocks/CU, so
// __launch_bounds__(256,2) -> VGPR cap 256 >> the ~100 this loop needs.
// Bitwise-identical output: wave w covers the identical a-tile set/order
// (w+4t, t ascending); qA/qB chains per qt are bit-identical to the old
// blocks'; the reduction runs twice (qt 0-3 -> psum[j0], qt 4-7 ->
// psum[j1]) in the exact old thread/shuffle order; final_kernel unchanged.
// XCD swizzle rebuilt bijectively for 512 (512%8==0): 64 contiguous
// logical ids per XCD = 4 (b,dir) A-packs = 512 KB, L2-resident.
__global__ __launch_bounds__(256, 2) void chamfer_mfma_kernel(
        const f16x8* __restrict__ predA, const f16x8* __restrict__ predB,
        const f16x8* __restrict__ tgtA, const f16x8* __restrict__ tgtB,
        const float* __restrict__ czero, float* __restrict__ psum) {
    int bid = blockIdx.x;
    int lin = (bid & 7) * 64 + (bid >> 3);    // XCD-contiguous logical id
    int qg8 = lin & 15; lin >>= 4;            // qg8(16) fastest, b(16), dir(2)
    int b   = lin & 15; lin >>= 4;
    int dir = lin;                            // 0: queries=pred, refs=target
    int j0 = dir * 512 + b * 32 + qg8 * 2;    // old logical psum slots
    int j1 = j0 + 1;

    const f16x8* __restrict__ Apack = dir ? predA : tgtA;  // refs
    const f16x8* __restrict__ Bpack = dir ? tgtB  : predB; // queries

    int tid = threadIdx.x;
    int w = tid >> 6, l = tid & 63;

    __shared__ float comb[4][8][64];

    f16x8 bq[8];
    #pragma unroll
    for (int qt = 0; qt < 8; ++qt)
        bq[qt] = Bpack[((size_t)(b * 128 + qg8 * 8 + qt)) * 64 + l];

    // opaque zero C-operand (value IS zero; provenance hidden from compiler)
    f32x16 cz = *(const f32x16*)czero;

    float qA[8], qB[8];
    #pragma unroll
    for (int qt = 0; qt < 8; ++qt) { qA[qt] = QMIN0; qB[qt] = QMIN0; }

    size_t abase = ((size_t)(b * 128)) * 64 + (size_t)w * 64 + l;
    #pragma unroll 4
    for (int t = 0; t < 32; ++t) {
        f16x8 a = Apack[abase + (size_t)t * 256];
        #pragma unroll
        for (int qt = 0; qt < 8; ++qt) {
            f32x16 d = __builtin_amdgcn_mfma_f32_32x32x16_f16(a, bq[qt], cz, 0, 0, 0);
            #pragma unroll
            for (int i = 0; i < 4; ++i) {
                qA[qt] = fminf(fminf(qA[qt], d[4 * i + 0]), d[4 * i + 1]);  // -> v_min3
                qB[qt] = fminf(fminf(qB[qt], d[4 * i + 2]), d[4 * i + 3]);  // -> v_min3
            }
        }
    }

    #pragma unroll
    for (int qt = 0; qt < 8; ++qt) comb[w][qt][l] = fminf(qA[qt], qB[qt]);
    __syncthreads();

    // Two independent reductions, each the EXACT old-block computation.
    float c0 = 0.0f, c1 = 0.0f;
    if (tid < 128) {
        int qt = tid >> 5, c = tid & 31;
        float m0 = QMIN0, m1 = QMIN0;
        #pragma unroll
        for (int ww = 0; ww < 4; ++ww)
            #pragma unroll
            for (int h = 0; h < 2; ++h) {
                m0 = fminf(m0, comb[ww][qt][h * 32 + c]);
                m1 = fminf(m1, comb[ww][qt + 4][h * 32 + c]);
            }
        // m < -1e4 marks an invalid query (w_q = -WBIG); contributes 0
        c0 = (m0 < -1e4f) ? 0.0f : sqrtf(fmaxf(m0, 1e-12f));
        c1 = (m1 < -1e4f) ? 0.0f : sqrtf(fmaxf(m1, 1e-12f));
    }
    for (int off = 32; off; off >>= 1) {
        c0 += __shfl_down(c0, off, 64);
        c1 += __shfl_down(c1, off, 64);
    }
    __shared__ float ps0[4], ps1[4];
    if ((tid & 63) == 0) { ps0[tid >> 6] = c0; ps1[tid >> 6] = c1; }
    __syncthreads();
    if (tid == 0) {
        psum[j0] = ps0[0] + ps0[1] + ps0[2] + ps0[3];
        psum[j1] = ps1[0] + ps1[1] + ps1[2] + ps1[3];
    }
}

__global__ __launch_bounds__(256) void final_kernel(
        const unsigned int* __restrict__ cnt4, const float* __restrict__ psum,
        float* __restrict__ out) {
    int t = threadIdx.x;
    unsigned int c = 0;
    float s = 0.0f;
    #pragma unroll
    for (int i = 0; i < 4; ++i) {
        c += cnt4[t + 256 * i];
        s += psum[t + 256 * i];
    }
    for (int off = 32; off; off >>= 1) {
        c += __shfl_down(c, off, 64);
        s += __shfl_down(s, off, 64);
    }
    __shared__ unsigned int cs[4];
    __shared__ float ss[4];
    if ((t & 63) == 0) { cs[t >> 6] = c; ss[t >> 6] = s; }
    __syncthreads();
    if (t == 0) {
        unsigned int C = cs[0] + cs[1] + cs[2] + cs[3];
        float S = ss[0] + ss[1] + ss[2] + ss[3];
        out[0] = S * 0.5f / ((float)C + 1e-8f);
    }
}

extern "C" void kernel_launch(void* const* d_in, const int* in_sizes, int n_in,
                              void* d_out, int out_size, void* d_ws, size_t ws_size,
                              hipStream_t stream) {
    const float* pred = (const float*)d_in[0];
    const float* target = (const float*)d_in[1];
    const int* mask = (const int*)d_in[2];
    float* out = (float*)d_out;

    // ws: [predA 2M | predB 2M | tgtA 2M | tgtB 2M | psum 4K | cnt4 4K | czero 64B]
    char* ws = (char*)d_ws;
    size_t off = 0;
    f16x8* predA = (f16x8*)(ws + off); off += FRAG_BYTES;
    f16x8* predB = (f16x8*)(ws + off); off += FRAG_BYTES;
    f16x8* tgtA  = (f16x8*)(ws + off); off += FRAG_BYTES;
    f16x8* tgtB  = (f16x8*)(ws + off); off += FRAG_BYTES;
    float* psum = (float*)(ws + off); off += NPSUM * sizeof(float);
    unsigned int* cnt4 = (unsigned int*)(ws + off); off += 1024 * sizeof(unsigned int);
    float* czero = (float*)(ws + off);

    prep_kernel<<<NPTS / 256, 256, 0, stream>>>(
        pred, target, mask, predA, predB, tgtA, tgtB, cnt4, czero);
    chamfer_mfma_kernel<<<MGRID, 256, 0, stream>>>(
        predA, predB, tgtA, tgtB, czero, psum);
    final_kernel<<<1, 256, 0, stream>>>(cnt4, psum, out);
}